// Round 7
// baseline (3526.114 us; speedup 1.0000x reference)
//
#include <hip/hip_runtime.h>

// Problem dims (fixed)
#define BATCH 32
#define SEQ   512
#define DMOD  1024
#define DFFN  4096
#define NHEAD 16
#define DHEAD 64
#define NLAY  4
#define NTOK  (BATCH * SEQ)   // 16384

typedef __attribute__((ext_vector_type(8))) short short8;
typedef __attribute__((ext_vector_type(4))) float f32x4;
typedef unsigned int uint32;

__device__ __forceinline__ unsigned short f2bf(float f) {
  uint32 u = __builtin_bit_cast(uint32, f);
  u += 0x7fffu + ((u >> 16) & 1u);             // RNE
  return (unsigned short)(u >> 16);
}
__device__ __forceinline__ float gelu_f(float x) {
  float u = 0.7978845608028654f * (x + 0.044715f * x * x * x);
  u = fminf(fmaxf(u, -15.f), 15.f);
  float e = __expf(2.f * u);
  return 0.5f * x * (1.f + (e - 1.f) / (e + 1.f));
}

#define GLOAD16(g, l) __builtin_amdgcn_global_load_lds( \
    (const __attribute__((address_space(1))) void*)(g), \
    (__attribute__((address_space(3))) void*)(l), 16, 0, 0)

#define MFMA16(a, b, c) __builtin_amdgcn_mfma_f32_16x16x32_bf16((a), (b), (c), 0, 0, 0)
#define FENCE asm volatile("" ::: "memory")
#define BARRIER do { FENCE; __builtin_amdgcn_s_barrier(); FENCE; } while (0)

// ---------------- positional encoding table: pe[l][d], 512x1024 ----------------
__global__ __launch_bounds__(256) void pe_kernel(float* __restrict__ pe) {
  const int idx = blockIdx.x * 256 + threadIdx.x;   // 0 .. 512*512-1 (pairs)
  const int l = idx >> 9;
  const int i = idx & 511;
  const float dv = __expf((float)(2 * i) * (-9.210340371976184f / (float)DMOD));
  const float a = (float)l * dv;
  pe[(size_t)l * DMOD + 2 * i]     = sinf(a);
  pe[(size_t)l * DMOD + 2 * i + 1] = cosf(a);
}

// ---------------- x + pe + speaker -> (optional f32) + bf16 ----------------
__global__ __launch_bounds__(256) void prep_kernel(
    const float* __restrict__ x, const float* __restrict__ pe, const float* __restrict__ spk,
    float* __restrict__ of32, unsigned short* __restrict__ o16)
{
  const size_t id4 = (size_t)blockIdx.x * 256 + threadIdx.x;  // over B*L*D/4
  const size_t e = id4 * 4;
  const int b  = (int)(e >> 19);
  const int ld = (int)(e & ((1u << 19) - 1));
  const int d  = (int)(e & 1023);
  float4 xv = ((const float4*)x)[id4];
  float4 pv = ((const float4*)pe)[ld >> 2];
  float4 sv = ((const float4*)spk)[(size_t)b * 256 + (d >> 2)];
  float4 o;
  o.x = xv.x + pv.x + sv.x;
  o.y = xv.y + pv.y + sv.y;
  o.z = xv.z + pv.z + sv.z;
  o.w = xv.w + pv.w + sv.w;
  if (of32) ((float4*)of32)[id4] = o;
  ushort4 h;
  h.x = f2bf(o.x); h.y = f2bf(o.y); h.z = f2bf(o.z); h.w = f2bf(o.w);
  ((ushort4*)o16)[id4] = h;
}

// ---------------- merged per-layer weight transpose: all 6 weights ----------------
// W [K][N] f32 -> Wt [N][K] bf16.  3072 blocks: [0,1024) QKVO, [1024,2048) W1, [2048,3072) W2.
__global__ __launch_bounds__(256) void wtrans_all(
    const float* __restrict__ Wq, const float* __restrict__ Wk,
    const float* __restrict__ Wv, const float* __restrict__ Wo,
    const float* __restrict__ W1, const float* __restrict__ W2, int layer,
    unsigned short* __restrict__ Wqt, unsigned short* __restrict__ Wkt,
    unsigned short* __restrict__ Wvt, unsigned short* __restrict__ Wot,
    unsigned short* __restrict__ W1t, unsigned short* __restrict__ W2t)
{
  __shared__ float tile[64][65];
  const int bid = blockIdx.x;
  const float* W; unsigned short* Wt; int K, N, bx, by;
  if (bid < 1024) {
    const int which = bid >> 8, r = bid & 255;
    bx = r & 15; by = r >> 4; K = DMOD; N = DMOD;
    const size_t off = (size_t)layer * DMOD * DMOD;
    W  = (which == 0 ? Wq : which == 1 ? Wk : which == 2 ? Wv : Wo) + off;
    Wt = (which == 0 ? Wqt : which == 1 ? Wkt : which == 2 ? Wvt : Wot);
  } else if (bid < 2048) {
    const int r = bid - 1024;
    bx = r & 63; by = r >> 6; K = DMOD; N = DFFN;
    W = W1 + (size_t)layer * DMOD * DFFN; Wt = W1t;
  } else {
    const int r = bid - 2048;
    bx = r & 15; by = r >> 4; K = DFFN; N = DMOD;
    W = W2 + (size_t)layer * DMOD * DFFN; Wt = W2t;
  }
  const int n0 = bx * 64, k0 = by * 64;
  const int tx = threadIdx.x & 63, ty = threadIdx.x >> 6;
  #pragma unroll
  for (int i = 0; i < 16; i++) {
    int r = ty + 4 * i;
    tile[r][tx] = W[(size_t)(k0 + r) * N + n0 + tx];
  }
  __syncthreads();
  #pragma unroll
  for (int i = 0; i < 16; i++) {
    int rn = ty + 4 * i;
    Wt[(size_t)(n0 + rn) * K + k0 + tx] = f2bf(tile[tx][rn]);
  }
}

// ---------------- LayerNorm: one block per row (1024 cols) ----------------
template<int WRITE_F32>
__global__ __launch_bounds__(256) void ln_kernel(
    const float* __restrict__ x, const float* __restrict__ g, const float* __restrict__ bta,
    float* __restrict__ of32, unsigned short* __restrict__ o16)
{
  const int row = blockIdx.x;
  const int t = threadIdx.x;
  const float4 v = ((const float4*)(x + (size_t)row * DMOD))[t];
  float s  = v.x + v.y + v.z + v.w;
  float s2 = v.x*v.x + v.y*v.y + v.z*v.z + v.w*v.w;
  #pragma unroll
  for (int off = 32; off > 0; off >>= 1) {
    s  += __shfl_down(s, off);
    s2 += __shfl_down(s2, off);
  }
  __shared__ float red[8];
  if ((t & 63) == 0) { red[(t >> 6) * 2] = s; red[(t >> 6) * 2 + 1] = s2; }
  __syncthreads();
  const float sum  = red[0] + red[2] + red[4] + red[6];
  const float sum2 = red[1] + red[3] + red[5] + red[7];
  const float mean = sum * (1.f / (float)DMOD);
  const float var  = sum2 * (1.f / (float)DMOD) - mean * mean;
  const float rstd = rsqrtf(var + 1e-6f);
  const float4 gg = ((const float4*)g)[t];
  const float4 bb = ((const float4*)bta)[t];
  float4 o;
  o.x = (v.x - mean) * rstd * gg.x + bb.x;
  o.y = (v.y - mean) * rstd * gg.y + bb.y;
  o.z = (v.z - mean) * rstd * gg.z + bb.z;
  o.w = (v.w - mean) * rstd * gg.w + bb.w;
  if (WRITE_F32) ((float4*)of32)[(size_t)row * 256 + t] = o;
  ushort4 h;
  h.x = f2bf(o.x); h.y = f2bf(o.y); h.z = f2bf(o.z); h.w = f2bf(o.w);
  ((ushort4*)o16)[(size_t)row * 256 + t] = h;
}

// ---------------- GEMM 256x256, 8 waves, 4-phase/K-tile pipeline ----------------
// No sched_barrier / lgkm pins (m141): compiler emits progressive lgkmcnt waits.
// Reads per phase balanced 8/4/8/4. Stage ledger (2 loads per st call):
//   P1: B(kt+1,ks1)+A(kt+1,ks1) -> buf^1 ; P3: A(kt+2,ks0)+B(kt+2,ks0) -> buf
//   P4: vmcnt(4) leaves P3(kt)'s 4 loads; confirms all of tile kt+1.
// Every LDS slot is re-staged >=1 barrier after its last read (checked).
// LDS bank-swizzle c^((row>>1)&3) both-sides (round-5 verified, 0 conflicts).
// EPI: 0 bias->bf16 ; 1 bias+gelu->bf16 ; 2 bias+res->f32 ; 3 bias+inplace->f32 ;
//      4 bias->bf16 V^T [b][ch][l] ; 5 bias,*0.125 ->bf16 (Q).
// bf16 epilogues (0/1/4/5) bounce through LDS for coalesced 16B stores.
template<int EPI>
__global__ __launch_bounds__(512, 2) void gemm256(
    const unsigned short* __restrict__ A, const unsigned short* __restrict__ Bt,
    const float* __restrict__ bias, const float* __restrict__ res,
    void* outp, int N, int K)
{
  __shared__ unsigned short Sh[2][2][2][256 * 32];  // [op][buf][ks] = 128 KB
  const int t = threadIdx.x;
  const int lane = t & 63, w = t >> 6;
  const int wm = w >> 2, wn = w & 3;                // 2 x 4 wave grid
  const int g = lane >> 4, rm = lane & 15;

  // XCD-aware bijective remap (all grids %8 == 0)
  const int nwg = gridDim.x * gridDim.y;
  const int hid = blockIdx.y * gridDim.x + blockIdx.x;
  const int wid = (hid & 7) * (nwg >> 3) + (hid >> 3);
  const int bx = wid % gridDim.x, by = wid / gridDim.x;
  const size_t tm = (size_t)by * 256;
  const size_t tn = (size_t)bx * 256;

  const int i0 = t, i1 = 512 + t;
  const int r0 = i0 >> 2, r1 = i1 >> 2;
  const int sc0 = 8 * ((i0 & 3) ^ ((r0 >> 1) & 3));   // pre-swizzled source col
  const int sc1 = 8 * ((i1 & 3) ^ ((r1 >> 1) & 3));
  const unsigned short* Abase = A + tm * (size_t)K;
  const unsigned short* Bbase = Bt + tn * (size_t)K;

  auto stA = [&](int kt, int ks, int bf) {
    const int k0 = kt * 64 + ks * 32;
    GLOAD16(Abase + (size_t)r0 * K + k0 + sc0, &Sh[0][bf][ks][i0 * 8]);
    GLOAD16(Abase + (size_t)r1 * K + k0 + sc1, &Sh[0][bf][ks][i1 * 8]);
  };
  auto stB = [&](int kt, int ks, int bf) {
    const int k0 = kt * 64 + ks * 32;
    GLOAD16(Bbase + (size_t)r0 * K + k0 + sc0, &Sh[1][bf][ks][i0 * 8]);
    GLOAD16(Bbase + (size_t)r1 * K + k0 + sc1, &Sh[1][bf][ks][i1 * 8]);
  };

  // swizzled fragment read offsets (bytes within a [256][32] half) — k-invariant
  int aoff[8], boff[4];
  #pragma unroll
  for (int fm = 0; fm < 8; fm++) {
    const int r = wm * 128 + fm * 16 + rm;
    aoff[fm] = r * 64 + ((g * 16) ^ (((r >> 1) & 3) << 4));
  }
  #pragma unroll
  for (int fn = 0; fn < 4; fn++) {
    const int r = wn * 64 + fn * 16 + rm;
    boff[fn] = r * 64 + ((g * 16) ^ (((r >> 1) & 3) << 4));
  }

  f32x4 acc[8][4];
  #pragma unroll
  for (int i = 0; i < 8; i++)
    #pragma unroll
    for (int j = 0; j < 4; j++)
      acc[i][j] = (f32x4){0.f, 0.f, 0.f, 0.f};

  const int nt = K >> 6;   // BK = 64
  // prologue: tile0 (8 loads) + {A,B}(1,ks0) (4 loads); vmcnt(4) -> tile0 ready
  stA(0, 0, 0); stB(0, 0, 0); stA(0, 1, 0); stB(0, 1, 0);
  stA(1, 0, 1); stB(1, 0, 1);
  asm volatile("s_waitcnt vmcnt(4)" ::: "memory");
  BARRIER;

  for (int kt = 0; kt < nt; kt++) {
    const int bf = kt & 1;
    const char* pA0 = (const char*)Sh[0][bf][0];
    const char* pA1 = (const char*)Sh[0][bf][1];
    const char* pB0 = (const char*)Sh[1][bf][0];
    const char* pB1 = (const char*)Sh[1][bf][1];
    short8 a0, a1, a2, a3, b0, b1, b2, b3;

    // ---- P1: read A.ks0[0-3] + B.ks0[0-3]; stage B(kt+1,ks1), A(kt+1,ks1) ----
    a0 = *(const short8*)(pA0 + aoff[0]); a1 = *(const short8*)(pA0 + aoff[1]);
    a2 = *(const short8*)(pA0 + aoff[2]); a3 = *(const short8*)(pA0 + aoff[3]);
    b0 = *(const short8*)(pB0 + boff[0]); b1 = *(const short8*)(pB0 + boff[1]);
    b2 = *(const short8*)(pB0 + boff[2]); b3 = *(const short8*)(pB0 + boff[3]);
    if (kt + 1 < nt) { stB(kt + 1, 1, bf ^ 1); stA(kt + 1, 1, bf ^ 1); }
    BARRIER;
    __builtin_amdgcn_s_setprio(1);
    acc[0][0] = MFMA16(a0, b0, acc[0][0]); acc[0][1] = MFMA16(a0, b1, acc[0][1]);
    acc[0][2] = MFMA16(a0, b2, acc[0][2]); acc[0][3] = MFMA16(a0, b3, acc[0][3]);
    acc[1][0] = MFMA16(a1, b0, acc[1][0]); acc[1][1] = MFMA16(a1, b1, acc[1][1]);
    acc[1][2] = MFMA16(a1, b2, acc[1][2]); acc[1][3] = MFMA16(a1, b3, acc[1][3]);
    acc[2][0] = MFMA16(a2, b0, acc[2][0]); acc[2][1] = MFMA16(a2, b1, acc[2][1]);
    acc[2][2] = MFMA16(a2, b2, acc[2][2]); acc[2][3] = MFMA16(a2, b3, acc[2][3]);
    acc[3][0] = MFMA16(a3, b0, acc[3][0]); acc[3][1] = MFMA16(a3, b1, acc[3][1]);
    acc[3][2] = MFMA16(a3, b2, acc[3][2]); acc[3][3] = MFMA16(a3, b3, acc[3][3]);
    __builtin_amdgcn_s_setprio(0);
    BARRIER;

    // ---- P2: read A.ks0[4-7]; MFMA fm4-7 x fn0-3 (b regs persist) ----
    a0 = *(const short8*)(pA0 + aoff[4]); a1 = *(const short8*)(pA0 + aoff[5]);
    a2 = *(const short8*)(pA0 + aoff[6]); a3 = *(const short8*)(pA0 + aoff[7]);
    BARRIER;
    __builtin_amdgcn_s_setprio(1);
    acc[4][0] = MFMA16(a0, b0, acc[4][0]); acc[4][1] = MFMA16(a0, b1, acc[4][1]);
    acc[4][2] = MFMA16(a0, b2, acc[4][2]); acc[4][3] = MFMA16(a0, b3, acc[4][3]);
    acc[5][0] = MFMA16(a1, b0, acc[5][0]); acc[5][1] = MFMA16(a1, b1, acc[5][1]);
    acc[5][2] = MFMA16(a1, b2, acc[5][2]); acc[5][3] = MFMA16(a1, b3, acc[5][3]);
    acc[6][0] = MFMA16(a2, b0, acc[6][0]); acc[6][1] = MFMA16(a2, b1, acc[6][1]);
    acc[6][2] = MFMA16(a2, b2, acc[6][2]); acc[6][3] = MFMA16(a2, b3, acc[6][3]);
    acc[7][0] = MFMA16(a3, b0, acc[7][0]); acc[7][1] = MFMA16(a3, b1, acc[7][1]);
    acc[7][2] = MFMA16(a3, b2, acc[7][2]); acc[7][3] = MFMA16(a3, b3, acc[7][3]);
    __builtin_amdgcn_s_setprio(0);
    BARRIER;

    // ---- P3: read A.ks1[0-3] + B.ks1[0-3]; stage A(kt+2,ks0), B(kt+2,ks0) ----
    a0 = *(const short8*)(pA1 + aoff[0]); a1 = *(const short8*)(pA1 + aoff[1]);
    a2 = *(const short8*)(pA1 + aoff[2]); a3 = *(const short8*)(pA1 + aoff[3]);
    b0 = *(const short8*)(pB1 + boff[0]); b1 = *(const short8*)(pB1 + boff[1]);
    b2 = *(const short8*)(pB1 + boff[2]); b3 = *(const short8*)(pB1 + boff[3]);
    if (kt + 2 < nt) { stA(kt + 2, 0, bf); stB(kt + 2, 0, bf); }
    BARRIER;
    __builtin_amdgcn_s_setprio(1);
    acc[0][0] = MFMA16(a0, b0, acc[0][0]); acc[0][1] = MFMA16(a0, b1, acc[0][1]);
    acc[0][2] = MFMA16(a0, b2, acc[0][2]); acc[0][3] = MFMA16(a0, b3, acc[0][3]);
    acc[1][0] = MFMA16(a1, b0, acc[1][0]); acc[1][1] = MFMA16(a1, b1, acc[1][1]);
    acc[1][2] = MFMA16(a1, b2, acc[1][2]); acc[1][3] = MFMA16(a1, b3, acc[1][3]);
    acc[2][0] = MFMA16(a2, b0, acc[2][0]); acc[2][1] = MFMA16(a2, b1, acc[2][1]);
    acc[2][2] = MFMA16(a2, b2, acc[2][2]); acc[2][3] = MFMA16(a2, b3, acc[2][3]);
    acc[3][0] = MFMA16(a3, b0, acc[3][0]); acc[3][1] = MFMA16(a3, b1, acc[3][1]);
    acc[3][2] = MFMA16(a3, b2, acc[3][2]); acc[3][3] = MFMA16(a3, b3, acc[3][3]);
    __builtin_amdgcn_s_setprio(0);
    BARRIER;

    // ---- P4: read A.ks1[4-7]; once-per-tile counted vmcnt ----
    a0 = *(const short8*)(pA1 + aoff[4]); a1 = *(const short8*)(pA1 + aoff[5]);
    a2 = *(const short8*)(pA1 + aoff[6]); a3 = *(const short8*)(pA1 + aoff[7]);
    if (kt < nt - 2)       asm volatile("s_waitcnt vmcnt(4)" ::: "memory");
    else if (kt == nt - 2) asm volatile("s_waitcnt vmcnt(0)" ::: "memory");
    BARRIER;
    __builtin_amdgcn_s_setprio(1);
    acc[4][0] = MFMA16(a0, b0, acc[4][0]); acc[4][1] = MFMA16(a0, b1, acc[4][1]);
    acc[4][2] = MFMA16(a0, b2, acc[4][2]); acc[4][3] = MFMA16(a0, b3, acc[4][3]);
    acc[5][0] = MFMA16(a1, b0, acc[5][0]); acc[5][1] = MFMA16(a1, b1, acc[5][1]);
    acc[5][2] = MFMA16(a1, b2, acc[5][2]); acc[5][3] = MFMA16(a1, b3, acc[5][3]);
    acc[6][0] = MFMA16(a2, b0, acc[6][0]); acc[6][1] = MFMA16(a2, b1, acc[6][1]);
    acc[6][2] = MFMA16(a2, b2, acc[6][2]); acc[6][3] = MFMA16(a2, b3, acc[6][3]);
    acc[7][0] = MFMA16(a3, b0, acc[7][0]); acc[7][1] = MFMA16(a3, b1, acc[7][1]);
    acc[7][2] = MFMA16(a3, b2, acc[7][2]); acc[7][3] = MFMA16(a3, b3, acc[7][3]);
    __builtin_amdgcn_s_setprio(0);
    BARRIER;
  }

  // ---------------- epilogue ----------------
  if (EPI == 2 || EPI == 3) {
    // f32 stores: 16 lanes x 4B contiguous = 64B spans, no amplification
    #pragma unroll
    for (int fn = 0; fn < 4; fn++) {
      const size_t gcol = tn + wn * 64 + fn * 16 + rm;
      const float bc = bias[gcol];
      #pragma unroll
      for (int fm = 0; fm < 8; fm++) {
        #pragma unroll
        for (int r = 0; r < 4; r++) {
          const size_t grow = tm + wm * 128 + fm * 16 + g * 4 + r;
          const size_t off = grow * (size_t)N + gcol;
          float v = acc[fm][fn][r] + bc;
          if (EPI == 2) ((float*)outp)[off] = v + res[off];
          else { float* op = (float*)outp; op[off] = v + op[off]; }
        }
      }
    }
  } else if (EPI == 4) {
    // V^T: LDS [ch 64][tok 128] (swizzled), then 16B stores along tokens
    unsigned short* eb = &Sh[0][0][0][0] + (size_t)w * 8192;   // 16 KB per wave
    #pragma unroll
    for (int fn = 0; fn < 4; fn++) {
      const float bc = bias[tn + wn * 64 + fn * 16 + rm];
      #pragma unroll
      for (int fm = 0; fm < 8; fm++)
        #pragma unroll
        for (int r = 0; r < 4; r++) {
          const int tok = fm * 16 + g * 4 + r;
          const int ch  = fn * 16 + rm;
          eb[ch * 128 + (tok ^ ((ch & 7) << 4))] = f2bf(acc[fm][fn][r] + bc);
        }
    }
    const int tok0 = (int)(tm) + wm * 128;
    const int bb = tok0 >> 9, l0 = tok0 & 511;
    #pragma unroll
    for (int pass = 0; pass < 16; pass++) {
      const int ch = pass * 4 + (lane >> 4);
      const int t8 = (lane & 15) * 8;
      short8 vv = *(const short8*)&eb[ch * 128 + (t8 ^ ((ch & 7) << 4))];
      *(short8*)((unsigned short*)outp +
                 ((size_t)bb * 1024 + tn + wn * 64 + ch) * 512 + l0 + t8) = vv;
    }
  } else {
    // bf16 row-major (EPI 0/1/5): LDS [row 128][col 64] (swizzled), 16B stores
    unsigned short* eb = &Sh[0][0][0][0] + (size_t)w * 8192;
    #pragma unroll
    for (int fn = 0; fn < 4; fn++) {
      const float bc = bias[tn + wn * 64 + fn * 16 + rm];
      #pragma unroll
      for (int fm = 0; fm < 8; fm++)
        #pragma unroll
        for (int r = 0; r < 4; r++) {
          float v = acc[fm][fn][r] + bc;
          if (EPI == 1) v = gelu_f(v);
          if (EPI == 5) v *= 0.125f;
          const int lr = fm * 16 + g * 4 + r;
          const int lc = fn * 16 + rm;
          eb[lr * 64 + (lc ^ (g << 4))] = f2bf(v);
        }
    }
    #pragma unroll
    for (int pass = 0; pass < 16; pass++) {
      const int lr = pass * 8 + (lane >> 3);
      const int lc8 = (lane & 7) * 8;
      const int q = (lr >> 2) & 3;
      short8 vv = *(const short8*)&eb[lr * 64 + (lc8 ^ (q << 4))];
      *(short8*)((unsigned short*)outp +
                 (tm + wm * 128 + lr) * (size_t)N + tn + wn * 64 + lc8) = vv;
    }
  }
}

// ---------------- MFMA flash attention (scale pre-folded into Q) ----------------
__global__ __launch_bounds__(256) void attn_mfma(
    const unsigned short* __restrict__ qb, const unsigned short* __restrict__ kb,
    const unsigned short* __restrict__ vt, unsigned short* __restrict__ ctx)
{
  __shared__ unsigned short Qs[128 * 64];      // 16 KB
  __shared__ unsigned short Ks[2][32 * 64];    //  8 KB
  __shared__ unsigned short Vs[2][64 * 32];    //  8 KB
  __shared__ unsigned short Ps[4][32 * 40];    // 10 KB
  const int t = threadIdx.x;
  const int lane = t & 63, w = t >> 6;
  const int g = lane >> 4, rm = lane & 15;
  const int qt = blockIdx.x, h = blockIdx.y, b = blockIdx.z;

  const unsigned short* qg = qb + ((size_t)(b * SEQ + qt * 128)) * DMOD + h * DHEAD;
  const unsigned short* kg = kb + ((size_t)(b * SEQ)) * DMOD + h * DHEAD;
  const unsigned short* vg = vt + ((size_t)(b * NHEAD + h)) * DHEAD * SEQ;  // [64][512]

  #pragma unroll
  for (int ii = 0; ii < 4; ii++) {
    const int i = ii * 256 + t;
    const int r = i >> 3, c = i & 7;
    const int bc = 16 * (c ^ (r & 7));
    GLOAD16(qg + (size_t)r * DMOD + (bc >> 1), Qs + (size_t)(ii * 256 + w * 64) * 8);
  }
  __syncthreads();

  short8 aq[2][2];
  #pragma unroll
  for (int fq = 0; fq < 2; fq++)
    #pragma unroll
    for (int kd = 0; kd < 2; kd++) {
      const int r = w * 32 + fq * 16 + rm;
      aq[fq][kd] = *(const short8*)((const char*)Qs + r * 128 + ((kd * 64 + g * 16) ^ ((r & 7) << 4)));
    }

  float mrow[2][4], lrow[2][4];
  f32x4 of[2][4];
  #pragma unroll
  for (int fq = 0; fq < 2; fq++) {
    #pragma unroll
    for (int j = 0; j < 4; j++) { mrow[fq][j] = -INFINITY; lrow[fq][j] = 0.f; }
    #pragma unroll
    for (int fd = 0; fd < 4; fd++) of[fq][fd] = (f32x4){0.f, 0.f, 0.f, 0.f};
  }

  auto stageK = [&](int kt, int bf) {
    const int r = t >> 3, c = t & 7;
    const int bc = 16 * (c ^ (r & 7));
    GLOAD16(kg + (size_t)(kt * 32 + r) * DMOD + (bc >> 1), Ks[bf] + (size_t)w * 512);
  };
  auto stageV = [&](int kt, int bf) {
    const int r = t >> 2, c = t & 3;
    const int bc = 16 * (c ^ (r & 3));
    GLOAD16(vg + (size_t)r * SEQ + kt * 32 + (bc >> 1), Vs[bf] + (size_t)w * 512);
  };

  stageK(0, 0); stageV(0, 0);
  __syncthreads();
  int buf = 0;

  for (int kt = 0; kt < SEQ / 32; kt++) {
    if (kt + 1 < SEQ / 32) { stageK(kt + 1, buf ^ 1); stageV(kt + 1, buf ^ 1); }

    f32x4 s[2][2];
    #pragma unroll
    for (int fq = 0; fq < 2; fq++)
      #pragma unroll
      for (int fk = 0; fk < 2; fk++) {
        f32x4 a = (f32x4){0.f, 0.f, 0.f, 0.f};
        #pragma unroll
        for (int kd = 0; kd < 2; kd++) {
          const int r = fk * 16 + rm;
          short8 bk = *(const short8*)((const char*)Ks[buf] + r * 128 + ((kd * 64 + g * 16) ^ ((r & 7) << 4)));
          a = MFMA16(aq[fq][kd], bk, a);
        }
        s[fq][fk] = a;
      }

    #pragma unroll
    for (int fq = 0; fq < 2; fq++) {
      #pragma unroll
      for (int j = 0; j < 4; j++) {
        const float s0 = s[fq][0][j];
        const float s1 = s[fq][1][j];
        float mx = fmaxf(s0, s1);
        #pragma unroll
        for (int mk = 1; mk < 16; mk <<= 1) mx = fmaxf(mx, __shfl_xor(mx, mk));
        const float mo = mrow[fq][j];
        const float mn = fmaxf(mo, mx);
        const float corr = __expf(mo - mn);
        mrow[fq][j] = mn;
        const float p0 = __expf(s0 - mn);
        const float p1 = __expf(s1 - mn);
        float rs = p0 + p1;
        #pragma unroll
        for (int mk = 1; mk < 16; mk <<= 1) rs += __shfl_xor(rs, mk);
        lrow[fq][j] = lrow[fq][j] * corr + rs;
        #pragma unroll
        for (int fd = 0; fd < 4; fd++) of[fq][fd][j] *= corr;
        Ps[w][(fq * 16 + g * 4 + j) * 40 + rm]      = f2bf(p0);
        Ps[w][(fq * 16 + g * 4 + j) * 40 + 16 + rm] = f2bf(p1);
      }
    }

    #pragma unroll
    for (int fq = 0; fq < 2; fq++) {
      const short8 pa = *(const short8*)((const char*)Ps[w] + (fq * 16 + rm) * 80 + g * 16);
      #pragma unroll
      for (int fd = 0; fd < 4; fd++) {
        const int r = fd * 16 + rm;
        const short8 vb = *(const short8*)((const char*)Vs[buf] + r * 64 + ((g * 16) ^ ((r & 3) << 4)));
        of[fq][fd] = MFMA16(pa, vb, of[fq][fd]);
      }
    }

    __syncthreads();
    buf ^= 1;
  }

  #pragma unroll
  for (int fq = 0; fq < 2; fq++)
    #pragma unroll
    for (int j = 0; j < 4; j++) {
      const float inv = 1.f / lrow[fq][j];
      const size_t q = (size_t)b * SEQ + qt * 128 + w * 32 + fq * 16 + g * 4 + j;
      #pragma unroll
      for (int fd = 0; fd < 4; fd++)
        ctx[q * DMOD + h * DHEAD + fd * 16 + rm] = f2bf(of[fq][fd][j] * inv);
    }
}

extern "C" void kernel_launch(void* const* d_in, const int* in_sizes, int n_in,
                              void* d_out, int out_size, void* d_ws, size_t ws_size,
                              hipStream_t stream) {
  const float* x_a   = (const float*)d_in[0];
  const float* x_b   = (const float*)d_in[1];
  const float* spk   = (const float*)d_in[2];
  const float* Wq    = (const float*)d_in[3];
  const float* bq    = (const float*)d_in[4];
  const float* Wk    = (const float*)d_in[5];
  const float* bk    = (const float*)d_in[6];
  const float* Wv    = (const float*)d_in[7];
  const float* bv    = (const float*)d_in[8];
  const float* Wo    = (const float*)d_in[9];
  const float* bo    = (const float*)d_in[10];
  const float* ln_g  = (const float*)d_in[11];
  const float* ln_b  = (const float*)d_in[12];
  const float* fln_g = (const float*)d_in[13];
  const float* fln_b = (const float*)d_in[14];
  const float* W1    = (const float*)d_in[15];
  const float* b1    = (const float*)d_in[16];
  const float* W2    = (const float*)d_in[17];
  const float* b2    = (const float*)d_in[18];
  float* out = (float*)d_out;           // also serves as the f32 x_b master (X)

  char* ws = (char*)d_ws;
  size_t o = 0;
  auto give = [&](size_t bytes) { char* p = ws + o; o += (bytes + 255) & ~(size_t)255; return p; };
  const size_t ACT2 = (size_t)NTOK * DMOD * 2;   // 32 MB bf16 activation

  // qb,kb,vt,ctx contiguous (128 MB), all dead during FFN -> `inter` aliases the span.
  unsigned short* qb16  = (unsigned short*)give(ACT2);
  unsigned short* kb16  = (unsigned short*)give(ACT2);
  unsigned short* vt16  = (unsigned short*)give(ACT2);       // V^T [b][h][d][l]
  unsigned short* ctx16 = (unsigned short*)give(ACT2);
  unsigned short* xa16  = (unsigned short*)give(ACT2);
  unsigned short* xbn16 = (unsigned short*)give(ACT2);
  float*          outf  = (float*)give((size_t)NTOK * DMOD * 4);   // 64 MB (residual stream)
  unsigned short* Wqt   = (unsigned short*)give((size_t)DMOD * DMOD * 2);
  unsigned short* Wkt   = (unsigned short*)give((size_t)DMOD * DMOD * 2);
  unsigned short* Wvt   = (unsigned short*)give((size_t)DMOD * DMOD * 2);
  unsigned short* Wot   = (unsigned short*)give((size_t)DMOD * DMOD * 2);
  unsigned short* W1t   = (unsigned short*)give((size_t)DMOD * DFFN * 2);
  unsigned short* W2t   = (unsigned short*)give((size_t)DMOD * DFFN * 2);
  float*          peb   = (float*)give((size_t)SEQ * DMOD * 4);
  unsigned short* inter = qb16;     // 128 MB span over qb16..ctx16
  (void)ws_size; (void)in_sizes; (void)n_in; (void)out_size;

  const dim3 blk(256);
  const dim3 blk512(512);

  pe_kernel<<<dim3((SEQ * (DMOD / 2)) / 256), blk, 0, stream>>>(peb);
  const int nprep = (NTOK * DMOD / 4) / 256;
  prep_kernel<<<dim3(nprep), blk, 0, stream>>>(x_a, peb, spk, nullptr, xa16);
  prep_kernel<<<dim3(nprep), blk, 0, stream>>>(x_b, peb, spk, out, xbn16);

  const dim3 g1024(DMOD / 256, NTOK / 256);   // (4,64) = 256 blocks
  const dim3 gW1(DFFN / 256, NTOK / 256);     // (16,64) = 1024 blocks
  const dim3 gW2(DMOD / 256, NTOK / 256);     // (4,64) = 256 blocks

  for (int i = 0; i < NLAY; i++) {
    wtrans_all<<<dim3(3072), blk, 0, stream>>>(Wq, Wk, Wv, Wo, W1, W2, i,
                                               Wqt, Wkt, Wvt, Wot, W1t, W2t);
    if (i != 0) {
      ln_kernel<1><<<dim3(NTOK), blk, 0, stream>>>(out, ln_g + (size_t)i * DMOD, ln_b + (size_t)i * DMOD, outf, xbn16);
    }
    gemm256<5><<<g1024, blk512, 0, stream>>>(xbn16, Wqt, bq + (size_t)i * DMOD, nullptr, qb16, DMOD, DMOD);
    gemm256<0><<<g1024, blk512, 0, stream>>>(xa16,  Wkt, bk + (size_t)i * DMOD, nullptr, kb16, DMOD, DMOD);
    gemm256<4><<<g1024, blk512, 0, stream>>>(xa16,  Wvt, bv + (size_t)i * DMOD, nullptr, vt16, DMOD, DMOD);
    attn_mfma<<<dim3(SEQ / 128, NHEAD, BATCH), blk, 0, stream>>>(qb16, kb16, vt16, ctx16);
    if (i == 0) {
      gemm256<2><<<g1024, blk512, 0, stream>>>(ctx16, Wot, bo + (size_t)i * DMOD, out, outf, DMOD, DMOD);
    } else {
      gemm256<3><<<g1024, blk512, 0, stream>>>(ctx16, Wot, bo + (size_t)i * DMOD, nullptr, outf, DMOD, DMOD);
    }
    ln_kernel<0><<<dim3(NTOK), blk, 0, stream>>>(outf, fln_g + (size_t)i * DMOD, fln_b + (size_t)i * DMOD, nullptr, xbn16);
    gemm256<1><<<gW1, blk512, 0, stream>>>(xbn16, W1t, b1 + (size_t)i * DFFN, nullptr, inter, DFFN, DMOD);
    gemm256<2><<<gW2, blk512, 0, stream>>>(inter, W2t, b2 + (size_t)i * DMOD, outf, out, DMOD, DFFN);
  }
}

// Round 8
// 3182.372 us; speedup vs baseline: 1.1080x; 1.1080x over previous
//
#include <hip/hip_runtime.h>

// Problem dims (fixed)
#define BATCH 32
#define SEQ   512
#define DMOD  1024
#define DFFN  4096
#define NHEAD 16
#define DHEAD 64
#define NLAY  4
#define NTOK  (BATCH * SEQ)   // 16384

typedef __attribute__((ext_vector_type(8))) short short8;
typedef __attribute__((ext_vector_type(4))) float f32x4;
typedef unsigned int uint32;

__device__ __forceinline__ unsigned short f2bf(float f) {
  uint32 u = __builtin_bit_cast(uint32, f);
  u += 0x7fffu + ((u >> 16) & 1u);             // RNE
  return (unsigned short)(u >> 16);
}
__device__ __forceinline__ float gelu_f(float x) {
  float u = 0.7978845608028654f * (x + 0.044715f * x * x * x);
  u = fminf(fmaxf(u, -15.f), 15.f);
  float e = __expf(2.f * u);
  return 0.5f * x * (1.f + (e - 1.f) / (e + 1.f));
}

#define GLOAD16(g, l) __builtin_amdgcn_global_load_lds( \
    (const __attribute__((address_space(1))) void*)(g), \
    (__attribute__((address_space(3))) void*)(l), 16, 0, 0)

#define MFMA16(a, b, c) __builtin_amdgcn_mfma_f32_16x16x32_bf16((a), (b), (c), 0, 0, 0)

// ---------------- positional encoding table: pe[l][d], 512x1024 ----------------
__global__ __launch_bounds__(256) void pe_kernel(float* __restrict__ pe) {
  const int idx = blockIdx.x * 256 + threadIdx.x;   // 0 .. 512*512-1 (pairs)
  const int l = idx >> 9;
  const int i = idx & 511;
  const float dv = __expf((float)(2 * i) * (-9.210340371976184f / (float)DMOD));
  const float a = (float)l * dv;
  pe[(size_t)l * DMOD + 2 * i]     = sinf(a);
  pe[(size_t)l * DMOD + 2 * i + 1] = cosf(a);
}

// ---------------- x + pe + speaker -> (optional f32) + bf16 ----------------
__global__ __launch_bounds__(256) void prep_kernel(
    const float* __restrict__ x, const float* __restrict__ pe, const float* __restrict__ spk,
    float* __restrict__ of32, unsigned short* __restrict__ o16)
{
  const size_t id4 = (size_t)blockIdx.x * 256 + threadIdx.x;  // over B*L*D/4
  const size_t e = id4 * 4;
  const int b  = (int)(e >> 19);
  const int ld = (int)(e & ((1u << 19) - 1));
  const int d  = (int)(e & 1023);
  float4 xv = ((const float4*)x)[id4];
  float4 pv = ((const float4*)pe)[ld >> 2];
  float4 sv = ((const float4*)spk)[(size_t)b * 256 + (d >> 2)];
  float4 o;
  o.x = xv.x + pv.x + sv.x;
  o.y = xv.y + pv.y + sv.y;
  o.z = xv.z + pv.z + sv.z;
  o.w = xv.w + pv.w + sv.w;
  if (of32) ((float4*)of32)[id4] = o;
  ushort4 h;
  h.x = f2bf(o.x); h.y = f2bf(o.y); h.z = f2bf(o.z); h.w = f2bf(o.w);
  ((ushort4*)o16)[id4] = h;
}

// ---------------- merged per-layer weight transpose: all 6 weights ----------------
__global__ __launch_bounds__(256) void wtrans_all(
    const float* __restrict__ Wq, const float* __restrict__ Wk,
    const float* __restrict__ Wv, const float* __restrict__ Wo,
    const float* __restrict__ W1, const float* __restrict__ W2, int layer,
    unsigned short* __restrict__ Wqt, unsigned short* __restrict__ Wkt,
    unsigned short* __restrict__ Wvt, unsigned short* __restrict__ Wot,
    unsigned short* __restrict__ W1t, unsigned short* __restrict__ W2t)
{
  __shared__ float tile[64][65];
  const int bid = blockIdx.x;
  const float* W; unsigned short* Wt; int K, N, bx, by;
  if (bid < 1024) {
    const int which = bid >> 8, r = bid & 255;
    bx = r & 15; by = r >> 4; K = DMOD; N = DMOD;
    const size_t off = (size_t)layer * DMOD * DMOD;
    W  = (which == 0 ? Wq : which == 1 ? Wk : which == 2 ? Wv : Wo) + off;
    Wt = (which == 0 ? Wqt : which == 1 ? Wkt : which == 2 ? Wvt : Wot);
  } else if (bid < 2048) {
    const int r = bid - 1024;
    bx = r & 63; by = r >> 6; K = DMOD; N = DFFN;
    W = W1 + (size_t)layer * DMOD * DFFN; Wt = W1t;
  } else {
    const int r = bid - 2048;
    bx = r & 15; by = r >> 4; K = DFFN; N = DMOD;
    W = W2 + (size_t)layer * DMOD * DFFN; Wt = W2t;
  }
  const int n0 = bx * 64, k0 = by * 64;
  const int tx = threadIdx.x & 63, ty = threadIdx.x >> 6;
  #pragma unroll
  for (int i = 0; i < 16; i++) {
    int r = ty + 4 * i;
    tile[r][tx] = W[(size_t)(k0 + r) * N + n0 + tx];
  }
  __syncthreads();
  #pragma unroll
  for (int i = 0; i < 16; i++) {
    int rn = ty + 4 * i;
    Wt[(size_t)(n0 + rn) * K + k0 + tx] = f2bf(tile[tx][rn]);
  }
}

// ---------------- LayerNorm: one block per row (1024 cols) ----------------
template<int WRITE_F32>
__global__ __launch_bounds__(256) void ln_kernel(
    const float* __restrict__ x, const float* __restrict__ g, const float* __restrict__ bta,
    float* __restrict__ of32, unsigned short* __restrict__ o16)
{
  const int row = blockIdx.x;
  const int t = threadIdx.x;
  const float4 v = ((const float4*)(x + (size_t)row * DMOD))[t];
  float s  = v.x + v.y + v.z + v.w;
  float s2 = v.x*v.x + v.y*v.y + v.z*v.z + v.w*v.w;
  #pragma unroll
  for (int off = 32; off > 0; off >>= 1) {
    s  += __shfl_down(s, off);
    s2 += __shfl_down(s2, off);
  }
  __shared__ float red[8];
  if ((t & 63) == 0) { red[(t >> 6) * 2] = s; red[(t >> 6) * 2 + 1] = s2; }
  __syncthreads();
  const float sum  = red[0] + red[2] + red[4] + red[6];
  const float sum2 = red[1] + red[3] + red[5] + red[7];
  const float mean = sum * (1.f / (float)DMOD);
  const float var  = sum2 * (1.f / (float)DMOD) - mean * mean;
  const float rstd = rsqrtf(var + 1e-6f);
  const float4 gg = ((const float4*)g)[t];
  const float4 bb = ((const float4*)bta)[t];
  float4 o;
  o.x = (v.x - mean) * rstd * gg.x + bb.x;
  o.y = (v.y - mean) * rstd * gg.y + bb.y;
  o.z = (v.z - mean) * rstd * gg.z + bb.z;
  o.w = (v.w - mean) * rstd * gg.w + bb.w;
  if (WRITE_F32) ((float4*)of32)[(size_t)row * 256 + t] = o;
  ushort4 h;
  h.x = f2bf(o.x); h.y = f2bf(o.y); h.z = f2bf(o.z); h.w = f2bf(o.w);
  ((ushort4*)o16)[(size_t)row * 256 + t] = h;
}

// ---------------- GEMM 128x256, 8 waves, single-buffer, 2 blocks/CU -------------
// Mechanism: cross-block overlap (m97/m114) — regs<=128 (launch_bounds 512,4),
// LDS 32 KB -> 2 blocks/CU; compiler-managed waitcnt; no setprio (m190).
// Swizzle c^((row>>1)&3) both-sides (round-5 verified, 0 conflicts).
// MODE 0: fused QKV via grid.z: z=0 Q (bias,*0.125,bf16), z=1 K (bias,bf16),
//         z=2 V (bias, bf16 V^T [b][ch][l]).  A = z?A1:A0.
// MODE 1: bias+gelu->bf16 (W1).  MODE 2: bias+res->f32.  MODE 3: bias+inplace->f32.
template<int MODE>
__global__ __launch_bounds__(512, 4) void gemm128(
    const unsigned short* __restrict__ A0, const unsigned short* __restrict__ A1,
    const unsigned short* __restrict__ B0, const unsigned short* __restrict__ B1,
    const unsigned short* __restrict__ B2,
    const float* __restrict__ bias0, const float* __restrict__ bias1,
    const float* __restrict__ bias2, const float* __restrict__ res,
    void* out0, void* out1, void* out2, int N, int K)
{
  __shared__ unsigned short Sh[16384];   // 32 KB: stage A[0,4096) B[4096,12288); epi all
  unsigned short* As = Sh;               // 128 x 32
  unsigned short* Bs = Sh + 4096;        // 256 x 32
  const int t = threadIdx.x;
  const int lane = t & 63, w = t >> 6;
  const int wm = w >> 2, wn = w & 3;     // 2(M) x 4(N) wave grid; wave owns 64x64
  const int g = lane >> 4, rm = lane & 15;

  // XCD-aware bijective remap over the whole (possibly 3D) grid
  const int gx = gridDim.x, gy = gridDim.y;
  const int nwg = gx * gy * gridDim.z;
  const int hid = (blockIdx.z * gy + blockIdx.y) * gx + blockIdx.x;
  const int wid = (hid & 7) * (nwg >> 3) + (hid >> 3);
  const int bx = wid % gx;
  const int rest = wid / gx;
  const int by = rest % gy;
  const int z  = rest / gy;              // 0 for 2D grids

  const unsigned short* A  = (MODE == 0 && z) ? A1 : A0;
  const unsigned short* Bt = (MODE == 0) ? (z == 0 ? B0 : z == 1 ? B1 : B2) : B0;
  const float* bias        = (MODE == 0) ? (z == 0 ? bias0 : z == 1 ? bias1 : bias2) : bias0;
  void* outp               = (MODE == 0) ? (z == 0 ? out0 : z == 1 ? out1 : out2) : out0;

  const size_t tm = (size_t)by * 128;
  const size_t tn = (size_t)bx * 256;

  // staging: A 512 chunks (1/thread), B 1024 chunks (2/thread); source pre-swizzled
  const int i0 = t, i1 = 512 + t;
  const int ra  = i0 >> 2;
  const int ca  = 8 * ((i0 & 3) ^ ((ra >> 1) & 3));
  const int rb1 = i1 >> 2;
  const int cb1 = 8 * ((i1 & 3) ^ ((rb1 >> 1) & 3));
  const unsigned short* Abase = A + (tm + ra) * (size_t)K + ca;
  const unsigned short* Bbase0 = Bt + (tn + ra) * (size_t)K + ca;
  const unsigned short* Bbase1 = Bt + (tn + rb1) * (size_t)K + cb1;

  // swizzled fragment read offsets (bytes) — k-invariant
  int aoff[4], boff[4];
  #pragma unroll
  for (int fm = 0; fm < 4; fm++) {
    const int r = wm * 64 + fm * 16 + rm;
    aoff[fm] = r * 64 + ((g * 16) ^ (((r >> 1) & 3) << 4));
  }
  #pragma unroll
  for (int fn = 0; fn < 4; fn++) {
    const int r = wn * 64 + fn * 16 + rm;
    boff[fn] = r * 64 + ((g * 16) ^ (((r >> 1) & 3) << 4));
  }

  f32x4 acc[4][4];
  #pragma unroll
  for (int i = 0; i < 4; i++)
    #pragma unroll
    for (int j = 0; j < 4; j++)
      acc[i][j] = (f32x4){0.f, 0.f, 0.f, 0.f};

  const int nt = K >> 5;
  for (int kt = 0; kt < nt; kt++) {
    const int k0 = kt * 32;
    GLOAD16(Abase + k0, &As[i0 * 8]);
    GLOAD16(Bbase0 + k0, &Bs[i0 * 8]);
    GLOAD16(Bbase1 + k0, &Bs[i1 * 8]);
    __syncthreads();                       // compiler drains vmcnt; hidden by co-block
    short8 a[4], b[4];
    #pragma unroll
    for (int fm = 0; fm < 4; fm++) a[fm] = *(const short8*)((const char*)As + aoff[fm]);
    #pragma unroll
    for (int fn = 0; fn < 4; fn++) b[fn] = *(const short8*)((const char*)Bs + boff[fn]);
    #pragma unroll
    for (int fm = 0; fm < 4; fm++)
      #pragma unroll
      for (int fn = 0; fn < 4; fn++)
        acc[fm][fn] = MFMA16(a[fm], b[fn], acc[fm][fn]);
    __syncthreads();
  }

  // ---------------- epilogue ----------------
  if (MODE == 2 || MODE == 3) {
    #pragma unroll
    for (int fn = 0; fn < 4; fn++) {
      const size_t gcol = tn + wn * 64 + fn * 16 + rm;
      const float bc = bias[gcol];
      #pragma unroll
      for (int fm = 0; fm < 4; fm++) {
        #pragma unroll
        for (int r = 0; r < 4; r++) {
          const size_t grow = tm + wm * 64 + fm * 16 + g * 4 + r;
          const size_t off = grow * (size_t)N + gcol;
          float v = acc[fm][fn][r] + bc;
          if (MODE == 2) ((float*)outp)[off] = v + res[off];
          else { float* op = (float*)outp; op[off] = v + op[off]; }
        }
      }
    }
  } else if (MODE == 0) {
    // z-switched bf16 epilogues, LDS-bounced; 4 waves per pass (32 KB budget)
    for (int half = 0; half < 2; half++) {
      __syncthreads();
      if ((w >> 2) == half) {
        unsigned short* eb = Sh + (w & 3) * 4096;
        if (z == 2) {
          // V^T slab [64 ch][64 tok]
          #pragma unroll
          for (int fn = 0; fn < 4; fn++) {
            const float bc = bias[tn + wn * 64 + fn * 16 + rm];
            #pragma unroll
            for (int fm = 0; fm < 4; fm++)
              #pragma unroll
              for (int r = 0; r < 4; r++) {
                const int tok = fm * 16 + g * 4 + r;
                const int ch  = fn * 16 + rm;
                eb[ch * 64 + (tok ^ ((ch & 7) << 3))] = f2bf(acc[fm][fn][r] + bc);
              }
          }
          const int tok0 = (int)tm + wm * 64;
          const int bb = tok0 >> 9, l0 = tok0 & 511;
          #pragma unroll
          for (int pass = 0; pass < 8; pass++) {
            const int ch = pass * 8 + (lane >> 3);
            const int t8 = (lane & 7) * 8;
            short8 vv = *(const short8*)&eb[ch * 64 + (t8 ^ ((ch & 7) << 3))];
            *(short8*)((unsigned short*)outp +
                       ((size_t)bb * 1024 + tn + wn * 64 + ch) * 512 + l0 + t8) = vv;
          }
        } else {
          // row-major slab [64 rows][64 cols]
          #pragma unroll
          for (int fn = 0; fn < 4; fn++) {
            const float bc = bias[tn + wn * 64 + fn * 16 + rm];
            #pragma unroll
            for (int fm = 0; fm < 4; fm++)
              #pragma unroll
              for (int r = 0; r < 4; r++) {
                float v = acc[fm][fn][r] + bc;
                if (z == 0) v *= 0.125f;
                const int lr = fm * 16 + g * 4 + r;
                const int lc = fn * 16 + rm;
                eb[lr * 64 + (lc ^ (g << 4))] = f2bf(v);
              }
          }
          #pragma unroll
          for (int pass = 0; pass < 8; pass++) {
            const int lr = pass * 8 + (lane >> 3);
            const int lc8 = (lane & 7) * 8;
            const int q = (lr >> 2) & 3;
            short8 vv = *(const short8*)&eb[lr * 64 + (lc8 ^ (q << 4))];
            *(short8*)((unsigned short*)outp +
                       (tm + wm * 64 + lr) * (size_t)N + tn + wn * 64 + lc8) = vv;
          }
        }
      }
    }
  } else {
    // MODE 1: gelu bf16 row-major, bounced
    for (int half = 0; half < 2; half++) {
      __syncthreads();
      if ((w >> 2) == half) {
        unsigned short* eb = Sh + (w & 3) * 4096;
        #pragma unroll
        for (int fn = 0; fn < 4; fn++) {
          const float bc = bias[tn + wn * 64 + fn * 16 + rm];
          #pragma unroll
          for (int fm = 0; fm < 4; fm++)
            #pragma unroll
            for (int r = 0; r < 4; r++) {
              const int lr = fm * 16 + g * 4 + r;
              const int lc = fn * 16 + rm;
              eb[lr * 64 + (lc ^ (g << 4))] = f2bf(gelu_f(acc[fm][fn][r] + bc));
            }
        }
        #pragma unroll
        for (int pass = 0; pass < 8; pass++) {
          const int lr = pass * 8 + (lane >> 3);
          const int lc8 = (lane & 7) * 8;
          const int q = (lr >> 2) & 3;
          short8 vv = *(const short8*)&eb[lr * 64 + (lc8 ^ (q << 4))];
          *(short8*)((unsigned short*)outp +
                     (tm + wm * 64 + lr) * (size_t)N + tn + wn * 64 + lc8) = vv;
        }
      }
    }
  }
}

// ---------------- MFMA flash attention (unchanged; Q pre-scaled) ----------------
__global__ __launch_bounds__(256) void attn_mfma(
    const unsigned short* __restrict__ qb, const unsigned short* __restrict__ kb,
    const unsigned short* __restrict__ vt, unsigned short* __restrict__ ctx)
{
  __shared__ unsigned short Qs[128 * 64];      // 16 KB
  __shared__ unsigned short Ks[2][32 * 64];    //  8 KB
  __shared__ unsigned short Vs[2][64 * 32];    //  8 KB
  __shared__ unsigned short Ps[4][32 * 40];    // 10 KB
  const int t = threadIdx.x;
  const int lane = t & 63, w = t >> 6;
  const int g = lane >> 4, rm = lane & 15;
  const int qt = blockIdx.x, h = blockIdx.y, b = blockIdx.z;

  const unsigned short* qg = qb + ((size_t)(b * SEQ + qt * 128)) * DMOD + h * DHEAD;
  const unsigned short* kg = kb + ((size_t)(b * SEQ)) * DMOD + h * DHEAD;
  const unsigned short* vg = vt + ((size_t)(b * NHEAD + h)) * DHEAD * SEQ;  // [64][512]

  #pragma unroll
  for (int ii = 0; ii < 4; ii++) {
    const int i = ii * 256 + t;
    const int r = i >> 3, c = i & 7;
    const int bc = 16 * (c ^ (r & 7));
    GLOAD16(qg + (size_t)r * DMOD + (bc >> 1), Qs + (size_t)(ii * 256 + w * 64) * 8);
  }
  __syncthreads();

  short8 aq[2][2];
  #pragma unroll
  for (int fq = 0; fq < 2; fq++)
    #pragma unroll
    for (int kd = 0; kd < 2; kd++) {
      const int r = w * 32 + fq * 16 + rm;
      aq[fq][kd] = *(const short8*)((const char*)Qs + r * 128 + ((kd * 64 + g * 16) ^ ((r & 7) << 4)));
    }

  float mrow[2][4], lrow[2][4];
  f32x4 of[2][4];
  #pragma unroll
  for (int fq = 0; fq < 2; fq++) {
    #pragma unroll
    for (int j = 0; j < 4; j++) { mrow[fq][j] = -INFINITY; lrow[fq][j] = 0.f; }
    #pragma unroll
    for (int fd = 0; fd < 4; fd++) of[fq][fd] = (f32x4){0.f, 0.f, 0.f, 0.f};
  }

  auto stageK = [&](int kt, int bf) {
    const int r = t >> 3, c = t & 7;
    const int bc = 16 * (c ^ (r & 7));
    GLOAD16(kg + (size_t)(kt * 32 + r) * DMOD + (bc >> 1), Ks[bf] + (size_t)w * 512);
  };
  auto stageV = [&](int kt, int bf) {
    const int r = t >> 2, c = t & 3;
    const int bc = 16 * (c ^ (r & 3));
    GLOAD16(vg + (size_t)r * SEQ + kt * 32 + (bc >> 1), Vs[bf] + (size_t)w * 512);
  };

  stageK(0, 0); stageV(0, 0);
  __syncthreads();
  int buf = 0;

  for (int kt = 0; kt < SEQ / 32; kt++) {
    if (kt + 1 < SEQ / 32) { stageK(kt + 1, buf ^ 1); stageV(kt + 1, buf ^ 1); }

    f32x4 s[2][2];
    #pragma unroll
    for (int fq = 0; fq < 2; fq++)
      #pragma unroll
      for (int fk = 0; fk < 2; fk++) {
        f32x4 a = (f32x4){0.f, 0.f, 0.f, 0.f};
        #pragma unroll
        for (int kd = 0; kd < 2; kd++) {
          const int r = fk * 16 + rm;
          short8 bk = *(const short8*)((const char*)Ks[buf] + r * 128 + ((kd * 64 + g * 16) ^ ((r & 7) << 4)));
          a = MFMA16(aq[fq][kd], bk, a);
        }
        s[fq][fk] = a;
      }

    #pragma unroll
    for (int fq = 0; fq < 2; fq++) {
      #pragma unroll
      for (int j = 0; j < 4; j++) {
        const float s0 = s[fq][0][j];
        const float s1 = s[fq][1][j];
        float mx = fmaxf(s0, s1);
        #pragma unroll
        for (int mk = 1; mk < 16; mk <<= 1) mx = fmaxf(mx, __shfl_xor(mx, mk));
        const float mo = mrow[fq][j];
        const float mn = fmaxf(mo, mx);
        const float corr = __expf(mo - mn);
        mrow[fq][j] = mn;
        const float p0 = __expf(s0 - mn);
        const float p1 = __expf(s1 - mn);
        float rs = p0 + p1;
        #pragma unroll
        for (int mk = 1; mk < 16; mk <<= 1) rs += __shfl_xor(rs, mk);
        lrow[fq][j] = lrow[fq][j] * corr + rs;
        #pragma unroll
        for (int fd = 0; fd < 4; fd++) of[fq][fd][j] *= corr;
        Ps[w][(fq * 16 + g * 4 + j) * 40 + rm]      = f2bf(p0);
        Ps[w][(fq * 16 + g * 4 + j) * 40 + 16 + rm] = f2bf(p1);
      }
    }

    #pragma unroll
    for (int fq = 0; fq < 2; fq++) {
      const short8 pa = *(const short8*)((const char*)Ps[w] + (fq * 16 + rm) * 80 + g * 16);
      #pragma unroll
      for (int fd = 0; fd < 4; fd++) {
        const int r = fd * 16 + rm;
        const short8 vb = *(const short8*)((const char*)Vs[buf] + r * 64 + ((g * 16) ^ ((r & 3) << 4)));
        of[fq][fd] = MFMA16(pa, vb, of[fq][fd]);
      }
    }

    __syncthreads();
    buf ^= 1;
  }

  #pragma unroll
  for (int fq = 0; fq < 2; fq++)
    #pragma unroll
    for (int j = 0; j < 4; j++) {
      const float inv = 1.f / lrow[fq][j];
      const size_t q = (size_t)b * SEQ + qt * 128 + w * 32 + fq * 16 + g * 4 + j;
      #pragma unroll
      for (int fd = 0; fd < 4; fd++)
        ctx[q * DMOD + h * DHEAD + fd * 16 + rm] = f2bf(of[fq][fd][j] * inv);
    }
}

extern "C" void kernel_launch(void* const* d_in, const int* in_sizes, int n_in,
                              void* d_out, int out_size, void* d_ws, size_t ws_size,
                              hipStream_t stream) {
  const float* x_a   = (const float*)d_in[0];
  const float* x_b   = (const float*)d_in[1];
  const float* spk   = (const float*)d_in[2];
  const float* Wq    = (const float*)d_in[3];
  const float* bq    = (const float*)d_in[4];
  const float* Wk    = (const float*)d_in[5];
  const float* bk    = (const float*)d_in[6];
  const float* Wv    = (const float*)d_in[7];
  const float* bv    = (const float*)d_in[8];
  const float* Wo    = (const float*)d_in[9];
  const float* bo    = (const float*)d_in[10];
  const float* ln_g  = (const float*)d_in[11];
  const float* ln_b  = (const float*)d_in[12];
  const float* fln_g = (const float*)d_in[13];
  const float* fln_b = (const float*)d_in[14];
  const float* W1    = (const float*)d_in[15];
  const float* b1    = (const float*)d_in[16];
  const float* W2    = (const float*)d_in[17];
  const float* b2    = (const float*)d_in[18];
  float* out = (float*)d_out;           // also serves as the f32 x_b master (X)

  char* ws = (char*)d_ws;
  size_t o = 0;
  auto give = [&](size_t bytes) { char* p = ws + o; o += (bytes + 255) & ~(size_t)255; return p; };
  const size_t ACT2 = (size_t)NTOK * DMOD * 2;   // 32 MB bf16 activation

  unsigned short* qb16  = (unsigned short*)give(ACT2);
  unsigned short* kb16  = (unsigned short*)give(ACT2);
  unsigned short* vt16  = (unsigned short*)give(ACT2);       // V^T [b][h][d][l]
  unsigned short* ctx16 = (unsigned short*)give(ACT2);
  unsigned short* xa16  = (unsigned short*)give(ACT2);
  unsigned short* xbn16 = (unsigned short*)give(ACT2);
  float*          outf  = (float*)give((size_t)NTOK * DMOD * 4);   // 64 MB (residual stream)
  unsigned short* Wqt   = (unsigned short*)give((size_t)DMOD * DMOD * 2);
  unsigned short* Wkt   = (unsigned short*)give((size_t)DMOD * DMOD * 2);
  unsigned short* Wvt   = (unsigned short*)give((size_t)DMOD * DMOD * 2);
  unsigned short* Wot   = (unsigned short*)give((size_t)DMOD * DMOD * 2);
  unsigned short* W1t   = (unsigned short*)give((size_t)DMOD * DFFN * 2);
  unsigned short* W2t   = (unsigned short*)give((size_t)DMOD * DFFN * 2);
  float*          peb   = (float*)give((size_t)SEQ * DMOD * 4);
  unsigned short* inter = qb16;     // 128 MB span over qb16..ctx16 (dead during FFN)
  (void)ws_size; (void)in_sizes; (void)n_in; (void)out_size;

  const dim3 blk(256);
  const dim3 blk512(512);

  pe_kernel<<<dim3((SEQ * (DMOD / 2)) / 256), blk, 0, stream>>>(peb);
  const int nprep = (NTOK * DMOD / 4) / 256;
  prep_kernel<<<dim3(nprep), blk, 0, stream>>>(x_a, peb, spk, nullptr, xa16);
  prep_kernel<<<dim3(nprep), blk, 0, stream>>>(x_b, peb, spk, out, xbn16);

  const dim3 gQKV(DMOD / 256, NTOK / 128, 3);   // (4,128,3) = 1536 blocks
  const dim3 gWO (DMOD / 256, NTOK / 128);      // (4,128)   = 512
  const dim3 gW1 (DFFN / 256, NTOK / 128);      // (16,128)  = 2048
  const dim3 gW2 (DMOD / 256, NTOK / 128);      // (4,128)   = 512

  for (int i = 0; i < NLAY; i++) {
    wtrans_all<<<dim3(3072), blk, 0, stream>>>(Wq, Wk, Wv, Wo, W1, W2, i,
                                               Wqt, Wkt, Wvt, Wot, W1t, W2t);
    if (i != 0) {
      ln_kernel<1><<<dim3(NTOK), blk, 0, stream>>>(out, ln_g + (size_t)i * DMOD, ln_b + (size_t)i * DMOD, outf, xbn16);
    }
    gemm128<0><<<gQKV, blk512, 0, stream>>>(
        xbn16, xa16, Wqt, Wkt, Wvt,
        bq + (size_t)i * DMOD, bk + (size_t)i * DMOD, bv + (size_t)i * DMOD,
        nullptr, qb16, kb16, vt16, DMOD, DMOD);
    attn_mfma<<<dim3(SEQ / 128, NHEAD, BATCH), blk, 0, stream>>>(qb16, kb16, vt16, ctx16);
    if (i == 0) {
      gemm128<2><<<gWO, blk512, 0, stream>>>(
          ctx16, nullptr, Wot, nullptr, nullptr,
          bo + (size_t)i * DMOD, nullptr, nullptr, out, outf, nullptr, nullptr, DMOD, DMOD);
    } else {
      gemm128<3><<<gWO, blk512, 0, stream>>>(
          ctx16, nullptr, Wot, nullptr, nullptr,
          bo + (size_t)i * DMOD, nullptr, nullptr, nullptr, outf, nullptr, nullptr, DMOD, DMOD);
    }
    ln_kernel<0><<<dim3(NTOK), blk, 0, stream>>>(outf, fln_g + (size_t)i * DMOD, fln_b + (size_t)i * DMOD, nullptr, xbn16);
    gemm128<1><<<gW1, blk512, 0, stream>>>(
        xbn16, nullptr, W1t, nullptr, nullptr,
        b1 + (size_t)i * DFFN, nullptr, nullptr, nullptr, inter, nullptr, nullptr, DFFN, DMOD);
    float* xout = (i == NLAY - 1) ? out : out;   // final residual lands in d_out either way
    gemm128<2><<<gW2, blk512, 0, stream>>>(
        inter, nullptr, W2t, nullptr, nullptr,
        b2 + (size_t)i * DMOD, nullptr, nullptr, outf, xout, nullptr, nullptr, DMOD, DFFN);
  }
}